// Round 3
// baseline (201.105 us; speedup 1.0000x reference)
//
#include <hip/hip_runtime.h>
#include <hip/hip_bf16.h>

#define EPSV 1e-5f

typedef __attribute__((ext_vector_type(8))) short short8;
typedef __attribute__((ext_vector_type(4))) float f32x4;
typedef __attribute__((ext_vector_type(2))) float f32x2;
typedef __attribute__((ext_vector_type(4))) unsigned u32x4;

// ws layout: w2 (1,179,648 B) | st (2,048 B)
#define W2_BYTES 1179648ull

// w_deform (o, C_in, 3, 3) fp32 -> w2 bf16 [o][K], K = p*288 + k*32 + c,
// C_in = p*32 + c (p = phase 0..7).  Also zero st.
__global__ __launch_bounds__(256) void wt2_kernel(const float* __restrict__ wd,
                                                  __hip_bfloat16* __restrict__ w2,
                                                  float* __restrict__ st) {
  int idx = blockIdx.x * 256 + threadIdx.x;   // o*2304 + p*288 + k*32 + c
  int c  = idx & 31;
  int r  = idx >> 5;          // o*72 + p*9 + k
  int k  = r % 9;
  int r2 = r / 9;             // o*8 + p
  int p  = r2 & 7;
  int o  = r2 >> 3;
  w2[idx] = __float2bfloat16(wd[(o * 256 + p * 32 + c) * 9 + k]);
  if (blockIdx.x < 2) st[blockIdx.x * 256 + threadIdx.x] = 0.f;
}

static __device__ __forceinline__ f32x2 unpk(unsigned u) {
  union { unsigned i; float f; } lo, hi;
  lo.i = u << 16;
  hi.i = u & 0xffff0000u;
  return (f32x2){lo.f, hi.f};
}

static __device__ __forceinline__ unsigned pkbf(float a, float b) {
  __hip_bfloat162 p = __float22bfloat162_rn(make_float2(a, b));
  return *(unsigned*)&p;
}

// Fused sample+GEMM, producer/consumer waves, 2 blocks/CU.
// Block = (b, 1-row band), 512 thr = 8 waves, grid 512 (2 blocks/CU -> two
// independent barrier cohorts per SIMD fill each other's latency holes).
//   waves 0-3 (consumers): 64(M) x 64(N) tile each; A global->reg (L2-resident
//     w2), B from LDS; 16 MFMA/iter.
//   waves 4-7 (producers, setprio 1): bilinear-sample next B tile (8 ch/thread,
//     4 uint4 gathers) into sB[(it+1)&1]; stream next phase's x-window rows.
// LDS 73.9 KB/block -> 2 blocks/CU.  ONE raw s_barrier per iter.
__global__ __launch_bounds__(512, 4) void fused_kernel(
    const float* __restrict__ x, const float* __restrict__ shp,
    const float* __restrict__ woff, const __hip_bfloat16* __restrict__ w2,
    float* __restrict__ out, float* __restrict__ st) {
  __shared__ __align__(16) unsigned short sX[2][8 * 64 * 32];  // 2 x 32 KB x-window
  __shared__ __align__(16) unsigned short sB[2][64 * 32];      // 2 x 4 KB B tiles
  __shared__ float sW[288];

  const int b    = blockIdx.x & 7;       // XCD swizzle: batch -> XCD
  const int band = blockIdx.x >> 3;      // 0..63 = output row h
  const int h    = band;
  const int t    = threadIdx.x;
  const int wv   = t >> 6, lane = t & 63;
  const int quad = lane >> 4, l15 = lane & 15;

  const float* xb = x + ((size_t)b << 20);
  const unsigned short* w2b = (const unsigned short*)w2;

  if (t < 288) sW[t] = woff[t];

  if (wv < 4) {
    // ============================ CONSUMER ============================
    const int cw = wv;                       // M-stripe: rows cw*64..+63
    const unsigned short* aro =
        w2b + (size_t)((cw << 6) + l15) * 2304 + (quad << 3);

    f32x4 acc[4][4];
#pragma unroll
    for (int mo = 0; mo < 4; ++mo)
#pragma unroll
      for (int np = 0; np < 4; ++np) acc[mo][np] = (f32x4){0.f, 0.f, 0.f, 0.f};

    short8 afc[4];                           // A frags for tile `it` (prefetched)
#pragma unroll
    for (int mo = 0; mo < 4; ++mo)
      afc[mo] = *(const short8*)(aro + (size_t)(mo << 4) * 2304);

    asm volatile("s_waitcnt lgkmcnt(0)" ::: "memory");  // sW writes
    asm volatile("s_barrier" ::: "memory");             // B1: sX[0]+sW ready
    asm volatile("s_barrier" ::: "memory");             // B2: tile0 in sB[0]

    for (int it = 0; it < 72; ++it) {
      const unsigned short* Bc = sB[it & 1];
#pragma unroll
      for (int np = 0; np < 4; ++np) {
        const int row = (np << 4) + l15;
        short8 bf = *(const short8*)&Bc[(row << 5) + ((quad ^ ((row >> 1) & 3)) << 3)];
#pragma unroll
        for (int mo = 0; mo < 4; ++mo)
          acc[mo][np] = __builtin_amdgcn_mfma_f32_16x16x32_bf16(afc[mo], bf, acc[mo][np], 0, 0, 0);
      }
      // prefetch A for it+1 AFTER last use; stays in flight across barrier.
      if (it < 71) {
#pragma unroll
        for (int mo = 0; mo < 4; ++mo)
          afc[mo] = *(const short8*)(aro + (size_t)(mo << 4) * 2304 + (size_t)((it + 1) << 5));
      }
      asm volatile("s_barrier" ::: "memory");
    }

    // GN partial stats (group = 8 consecutive o); shuffle sums px(l15) x o(r),
    // quad pairs land in the same gid.
#pragma unroll
    for (int mo = 0; mo < 4; ++mo) {
      float s = 0.f, q = 0.f;
#pragma unroll
      for (int np = 0; np < 4; ++np)
#pragma unroll
        for (int r = 0; r < 4; ++r) { float v = acc[mo][np][r]; s += v; q += v * v; }
#pragma unroll
      for (int m = 1; m < 16; m <<= 1) { s += __shfl_xor(s, m, 64); q += __shfl_xor(q, m, 64); }
      if (l15 == 0) {
        int gid = (b << 5) + (cw << 3) + (mo << 1) + (quad >> 1);
        atomicAdd(&st[gid], s);
        atomicAdd(&st[256 + gid], q);
      }
    }

    // C store: col(n)=l15 within 16, row(o)=quad*4+r per 16x16 block
    float* ob = out + (((size_t)((b << 8) + (cw << 6))) << 12) + (h << 6);
#pragma unroll
    for (int mo = 0; mo < 4; ++mo)
#pragma unroll
      for (int np = 0; np < 4; ++np)
#pragma unroll
        for (int r = 0; r < 4; ++r)
          ob[((size_t)((mo << 4) + (quad << 2) + r) << 12) + (np << 4) + l15] = acc[mo][np][r];
  } else {
    // ============================ PRODUCER ============================
    __builtin_amdgcn_s_setprio(1);           // producer = critical role
    const int pid = t - 256;                 // 0..255
    const int pxl = pid & 63;                // pixel (column) in row h
    const int c8  = pid >> 6;                // 0..3: channels c8*8..+7 of phase slab
    const int wslot = (c8 ^ ((pxl >> 1) & 3)) << 3;

    float a0 = shp[((size_t)(b * 4 + 0) << 12) + (h << 6) + pxl];
    float a1 = shp[((size_t)(b * 4 + 1) << 12) + (h << 6) + pxl];
    float a2 = shp[((size_t)(b * 4 + 2) << 12) + (h << 6) + pxl];
    float a3 = shp[((size_t)(b * 4 + 3) << 12) + (h << 6) + pxl];

    // ---- prologue: stage sX[0] (phase 0 window, rows h-3..h+4 clamped) ----
    {
      const float* xph = xb + ((size_t)(c8 << 3) << 12) + pxl;
#pragma unroll
      for (int j = 0; j < 8; ++j) {
        const int grow = min(max(h - 3 + j, 0), 63);
        float v[8];
#pragma unroll
        for (int jj = 0; jj < 8; ++jj) v[jj] = xph[(jj << 12) + (grow << 6)];
        *(u32x4*)&sX[0][(((j << 6) + pxl) << 5) + wslot] =
            (u32x4){pkbf(v[0], v[1]), pkbf(v[2], v[3]), pkbf(v[4], v[5]), pkbf(v[6], v[7])};
      }
    }

    // sample tap tk of phase tp (8 channels) for pixel (h,pxl) -> sB[buf]
    auto produce = [&](int tp, int tk, int buf) {
      const float* wp = &sW[(((tp >> 1) * 9 + tk)) << 3];
      float dy = wp[0]*a0 + wp[1]*a1 + wp[2]*a2 + wp[3]*a3;
      float dx = wp[4]*a0 + wp[5]*a1 + wp[6]*a2 + wp[7]*a3;
      float py  = dy + (float)(h + tk / 3 - 1);
      float pxp = dx + (float)(pxl + tk % 3 - 1);
      float y0f = floorf(py), x0f = floorf(pxp);
      float ly = py - y0f, lx = pxp - x0f;
      int y0 = (int)y0f, x0 = (int)x0f;
      float m_y0 = (y0 >=  0 && y0 <= 63) ? 1.f : 0.f;
      float m_y1 = (y0 >= -1 && y0 <= 62) ? 1.f : 0.f;
      float m_x0 = (x0 >=  0 && x0 <= 63) ? 1.f : 0.f;
      float m_x1 = (x0 >= -1 && x0 <= 62) ? 1.f : 0.f;
      float w00 = (1.f - ly) * (1.f - lx) * m_y0 * m_x0;
      float w01 = (1.f - ly) * lx         * m_y0 * m_x1;
      float w10 = ly         * (1.f - lx) * m_y1 * m_x0;
      float w11 = ly         * lx         * m_y1 * m_x1;
      int yc0 = min(max(y0, 0), 63),     yc1 = min(max(y0 + 1, 0), 63);
      int xc0 = min(max(x0, 0), 63),     xc1 = min(max(x0 + 1, 0), 63);
      int ry0 = min(max(yc0 - (h - 3), 0), 7);
      int ry1 = min(max(yc1 - (h - 3), 0), 7);
      const unsigned short* Xc = sX[tp & 1];
      const int z0 = (xc0 >> 1) & 3, z1 = (xc1 >> 1) & 3;
      uint4 Au = *(const uint4*)&Xc[(((ry0 << 6) + xc0) << 5) + ((c8 ^ z0) << 3)];
      uint4 Bu = *(const uint4*)&Xc[(((ry0 << 6) + xc1) << 5) + ((c8 ^ z1) << 3)];
      uint4 Cu = *(const uint4*)&Xc[(((ry1 << 6) + xc0) << 5) + ((c8 ^ z0) << 3)];
      uint4 Du = *(const uint4*)&Xc[(((ry1 << 6) + xc1) << 5) + ((c8 ^ z1) << 3)];
      unsigned ua[4] = {Au.x, Au.y, Au.z, Au.w};
      unsigned ub[4] = {Bu.x, Bu.y, Bu.z, Bu.w};
      unsigned uc[4] = {Cu.x, Cu.y, Cu.z, Cu.w};
      unsigned ud[4] = {Du.x, Du.y, Du.z, Du.w};
      unsigned ov[4];
#pragma unroll
      for (int j = 0; j < 4; ++j) {
        f32x2 v = unpk(ua[j]) * w00 + unpk(ub[j]) * w01
                + unpk(uc[j]) * w10 + unpk(ud[j]) * w11;
        ov[j] = pkbf(v.x, v.y);
      }
      *(u32x4*)&sB[buf][(pxl << 5) + ((c8 ^ ((pxl >> 1) & 3)) << 3)] =
          (u32x4){ov[0], ov[1], ov[2], ov[3]};
    };

    auto commit8 = [&](const float* v, int row, int nb) {
      *(u32x4*)&sX[nb][(((row << 6) + pxl) << 5) + wslot] =
          (u32x4){pkbf(v[0], v[1]), pkbf(v[2], v[3]), pkbf(v[4], v[5]), pkbf(v[6], v[7])};
    };

    asm volatile("s_waitcnt lgkmcnt(0)" ::: "memory");  // sX[0] writes done
    asm volatile("s_barrier" ::: "memory");             // B1

    produce(0, 0, 0);                                   // tile 0 -> sB[0]
    asm volatile("s_waitcnt lgkmcnt(0)" ::: "memory");
    asm volatile("s_barrier" ::: "memory");             // B2

    float xrA[8], xrB[8];
    int k = 0, phase = 0;
    for (int it = 0; it < 72; ++it) {
      // ---- x-window streaming for phase+1 (issue-early / commit-late) ----
      // k=0: issue r0,r1.  k=1: commit r0,r1, issue r2.  k=2..6: commit rk,
      // issue r(k+1).  k=7: commit r7.  First read of sX[next] at k=8.
      if (phase < 7) {
        const float* xph = xb + ((size_t)(((phase + 1) << 5) + (c8 << 3)) << 12) + pxl;
        if (k == 0) {
          const int g0 = min(max(h - 3, 0), 63);
          const int g1 = min(max(h - 2, 0), 63);
#pragma unroll
          for (int jj = 0; jj < 8; ++jj) xrA[jj] = xph[(jj << 12) + (g0 << 6)];
#pragma unroll
          for (int jj = 0; jj < 8; ++jj) xrB[jj] = xph[(jj << 12) + (g1 << 6)];
        } else if (k <= 7) {
          const int nb = (phase + 1) & 1;
          commit8(xrA, (k == 1) ? 0 : k, nb);
          if (k == 1) commit8(xrB, 1, nb);
          if (k <= 6) {
            const int grow = min(max(h - 3 + k + 1, 0), 63);
#pragma unroll
            for (int jj = 0; jj < 8; ++jj) xrA[jj] = xph[(jj << 12) + (grow << 6)];
          }
        }
      }
      // ---- produce tile it+1 into sB[(it+1)&1] ----
      if (it < 71) {
        const int tk = (k == 8) ? 0 : k + 1;
        const int tp = (k == 8) ? phase + 1 : phase;
        produce(tp, tk, (it + 1) & 1);
      }
      asm volatile("s_waitcnt lgkmcnt(0)" ::: "memory");  // LDS writes visible
      asm volatile("s_barrier" ::: "memory");
      if (++k == 9) { k = 0; ++phase; }
    }
  }
}

// Normalize + affine + ReLU from atomic sums (full-line nt store).
__global__ __launch_bounds__(256) void norm_kernel(float* __restrict__ o,
    const float* __restrict__ st, const float* __restrict__ gamma,
    const float* __restrict__ beta) {
  int idx = blockIdx.x * 256 + threadIdx.x;    // float4s: 2,097,152
  f32x4* p = (f32x4*)o;
  int c = (idx >> 10) & 255;
  int b = idx >> 18;
  int g = b * 32 + (c >> 3);
  const float invn = 1.f / 32768.f;
  float mu  = st[g] * invn;
  float var = st[256 + g] * invn - mu * mu;
  float ga = gamma[c] * rsqrtf(var + EPSV);
  float be = beta[c] - mu * ga;
  f32x4 v = p[idx];
  v.x = fmaxf(fmaf(v.x, ga, be), 0.f);
  v.y = fmaxf(fmaf(v.y, ga, be), 0.f);
  v.z = fmaxf(fmaf(v.z, ga, be), 0.f);
  v.w = fmaxf(fmaf(v.w, ga, be), 0.f);
  __builtin_nontemporal_store(v, &p[idx]);
}

extern "C" void kernel_launch(void* const* d_in, const int* in_sizes, int n_in,
                              void* d_out, int out_size, void* d_ws, size_t ws_size,
                              hipStream_t stream) {
  const float* x     = (const float*)d_in[0];
  const float* shp   = (const float*)d_in[1];
  const float* woff  = (const float*)d_in[2];
  const float* wdef  = (const float*)d_in[3];
  const float* gamma = (const float*)d_in[4];
  const float* beta  = (const float*)d_in[5];
  float* out = (float*)d_out;
  __hip_bfloat16* w2 = (__hip_bfloat16*)d_ws;
  float* st          = (float*)((char*)d_ws + W2_BYTES);

  hipLaunchKernelGGL(wt2_kernel,   dim3(2304), dim3(256), 0, stream, wdef, w2, st);
  hipLaunchKernelGGL(fused_kernel, dim3(512),  dim3(512), 0, stream, x, shp, woff, w2, out, st);
  hipLaunchKernelGGL(norm_kernel,  dim3(8192), dim3(256), 0, stream, out, st, gamma, beta);
}

// Round 4
// 179.532 us; speedup vs baseline: 1.1202x; 1.1202x over previous
//
#include <hip/hip_runtime.h>
#include <hip/hip_bf16.h>

#define EPSV 1e-5f

typedef __attribute__((ext_vector_type(8))) short short8;
typedef __attribute__((ext_vector_type(4))) float f32x4;
typedef __attribute__((ext_vector_type(2))) float f32x2;
typedef __attribute__((ext_vector_type(4))) unsigned u32x4;

// ws layout: w2 (1,179,648 B) | st (2,048 B)
#define W2_BYTES 1179648ull

// w_deform (o, C_in, 3, 3) fp32 -> w2 bf16 [o][K], K = p*288 + k*32 + c,
// C_in = p*32 + c (p = phase 0..7).  Also zero st.
__global__ __launch_bounds__(256) void wt2_kernel(const float* __restrict__ wd,
                                                  __hip_bfloat16* __restrict__ w2,
                                                  float* __restrict__ st) {
  int idx = blockIdx.x * 256 + threadIdx.x;   // o*2304 + p*288 + k*32 + c
  int c  = idx & 31;
  int r  = idx >> 5;          // o*72 + p*9 + k
  int k  = r % 9;
  int r2 = r / 9;             // o*8 + p
  int p  = r2 & 7;
  int o  = r2 >> 3;
  w2[idx] = __float2bfloat16(wd[(o * 256 + p * 32 + c) * 9 + k]);
  if (blockIdx.x < 2) st[blockIdx.x * 256 + threadIdx.x] = 0.f;
}

static __device__ __forceinline__ f32x2 unpk(unsigned u) {
  union { unsigned i; float f; } lo, hi;
  lo.i = u << 16;
  hi.i = u & 0xffff0000u;
  return (f32x2){lo.f, hi.f};
}

static __device__ __forceinline__ unsigned pkbf(float a, float b) {
  __hip_bfloat162 p = __float22bfloat162_rn(make_float2(a, b));
  return *(unsigned*)&p;
}

// Fused sample+GEMM, producer/consumer waves, K=64 rounds (2 taps/round).
// Block = (b, 2-row band), 512 thr = 8 waves, grid 256 (1 block/CU).
//   waves 0-3 (consumers): 64(M) x 128(N) tile; A global->reg (L2-resident w2),
//     B from LDS; 64 MFMA/round.
//   waves 4-7 (producers): each thread = (pixel, tap-slot) x 32 ch: 16
//     independent LDS gathers/round (2x ILP of R2); x-window staged 2-3
//     rows/round on a static schedule (issue-early/commit-late).
// 36 rounds, ONE raw s_barrier per round (half of R2's sync cost).
__global__ __launch_bounds__(512, 2) void fused_kernel(
    const float* __restrict__ x, const float* __restrict__ shp,
    const float* __restrict__ woff, const __hip_bfloat16* __restrict__ w2,
    float* __restrict__ out, float* __restrict__ st) {
  __shared__ __align__(16) unsigned short sX[2][8 * 64 * 32];  // 2 x 32 KB x-window
  __shared__ __align__(16) unsigned short sB[2][128 * 64];     // 2 x 16 KB K=64 tiles
  __shared__ float sW[288];

  const int b    = blockIdx.x & 7;       // XCD swizzle: batch -> XCD
  const int band = blockIdx.x >> 3;      // 0..31
  const int h0   = band << 1;
  const int t    = threadIdx.x;
  const int wv   = t >> 6, lane = t & 63;
  const int quad = lane >> 4, l15 = lane & 15;

  const float* xb = x + ((size_t)b << 20);
  const unsigned short* w2b = (const unsigned short*)w2;

  if (t < 288) sW[t] = woff[t];

  if (wv < 4) {
    // ============================ CONSUMER ============================
    const int cw = wv;                       // M-stripe: rows cw*64..+63
    const unsigned short* aro =
        w2b + (size_t)((cw << 6) + l15) * 2304 + (quad << 3);

    f32x4 acc[4][8];
#pragma unroll
    for (int mo = 0; mo < 4; ++mo)
#pragma unroll
      for (int np = 0; np < 8; ++np) acc[mo][np] = (f32x4){0.f, 0.f, 0.f, 0.f};

    short8 afc[2][4];                        // A frags for round `it`
#pragma unroll
    for (int ks = 0; ks < 2; ++ks)
#pragma unroll
      for (int mo = 0; mo < 4; ++mo)
        afc[ks][mo] = *(const short8*)(aro + (size_t)(mo << 4) * 2304 + (ks << 5));

    asm volatile("s_waitcnt lgkmcnt(0)" ::: "memory");  // sW writes
    asm volatile("s_barrier" ::: "memory");             // B1: sX[0]+sW ready
    asm volatile("s_barrier" ::: "memory");             // B2: tile0 in sB[0]

    for (int it = 0; it < 36; ++it) {
      const unsigned short* Bc = sB[it & 1];
#pragma unroll
      for (int np = 0; np < 8; ++np) {
        const int row = (np << 4) + l15;
#pragma unroll
        for (int ks = 0; ks < 2; ++ks) {
          short8 bf = *(const short8*)&Bc[(row << 6) +
                         ((((ks << 2) + quad) ^ (row & 7)) << 3)];
#pragma unroll
          for (int mo = 0; mo < 4; ++mo)
            acc[mo][np] = __builtin_amdgcn_mfma_f32_16x16x32_bf16(afc[ks][mo], bf, acc[mo][np], 0, 0, 0);
        }
      }
      // prefetch A for it+1 AFTER last use; stays in flight across barrier.
      if (it < 35) {
#pragma unroll
        for (int ks = 0; ks < 2; ++ks)
#pragma unroll
          for (int mo = 0; mo < 4; ++mo)
            afc[ks][mo] = *(const short8*)(aro + (size_t)(mo << 4) * 2304 +
                                           (size_t)((it + 1) << 6) + (ks << 5));
      }
      asm volatile("s_barrier" ::: "memory");
    }

    // GN partial stats (group = 8 consecutive o)
#pragma unroll
    for (int mo = 0; mo < 4; ++mo) {
      float s = 0.f, q = 0.f;
#pragma unroll
      for (int np = 0; np < 8; ++np)
#pragma unroll
        for (int r = 0; r < 4; ++r) { float v = acc[mo][np][r]; s += v; q += v * v; }
#pragma unroll
      for (int m = 1; m < 16; m <<= 1) { s += __shfl_xor(s, m, 64); q += __shfl_xor(q, m, 64); }
      if (l15 == 0) {
        int gid = (b << 5) + (cw << 3) + (mo << 1) + (quad >> 1);
        atomicAdd(&st[gid], s);
        atomicAdd(&st[256 + gid], q);
      }
    }

    // C store: col(n)=l15, row(o)=quad*4+r per 16x16 block
    float* ob = out + (((size_t)((b << 8) + (cw << 6))) << 12) + (band << 7);
#pragma unroll
    for (int mo = 0; mo < 4; ++mo)
#pragma unroll
      for (int np = 0; np < 8; ++np)
#pragma unroll
        for (int r = 0; r < 4; ++r)
          ob[((size_t)((mo << 4) + (quad << 2) + r) << 12) + (np << 4) + l15] = acc[mo][np][r];
  } else {
    // ============================ PRODUCER ============================
    const int pid     = t - 256;             // 0..255
    const int pxn     = pid & 127;           // band-local pixel n = hh*64+pxl
    const int tapslot = pid >> 7;            // 0/1: which tap of the K=64 pair
    const int pxl     = pxn & 63;
    const int h       = h0 + (pxn >> 6);
    const int spx     = pid & 63;            // x-stage: pixel
    const int sc8     = (pid >> 6) & 3;      // x-stage: 8-ch slot
    const int wslot   = (sc8 ^ ((spx >> 1) & 3)) << 3;

    float a0 = shp[((size_t)(b * 4 + 0) << 12) + (h << 6) + pxl];
    float a1 = shp[((size_t)(b * 4 + 1) << 12) + (h << 6) + pxl];
    float a2 = shp[((size_t)(b * 4 + 2) << 12) + (h << 6) + pxl];
    float a3 = shp[((size_t)(b * 4 + 3) << 12) + (h << 6) + pxl];

    // ---- prologue: stage sX[0] (slab 0 window, rows h0-3..h0+4 clamped) ----
    {
      const float* xph = xb + ((size_t)(sc8 << 3) << 12) + spx;
#pragma unroll
      for (int j = 0; j < 8; ++j) {
        const int grow = min(max(h0 - 3 + j, 0), 63);
        float v[8];
#pragma unroll
        for (int jj = 0; jj < 8; ++jj) v[jj] = xph[(jj << 12) + (grow << 6)];
        *(u32x4*)&sX[0][((((j << 6) + spx) << 5)) + wslot] =
            (u32x4){pkbf(v[0], v[1]), pkbf(v[2], v[3]), pkbf(v[4], v[5]), pkbf(v[6], v[7])};
      }
    }

    // sample global tap g (32 channels) for pixel (h,pxl) -> sB[buf]
    auto produce = [&](int g, int buf) {
      const int ph  = (g * 57) >> 9;         // g/9  (g < 72)
      const int tap = g - ph * 9;
      const int kr  = (tap * 11) >> 5;       // tap/3
      const int kc  = tap - kr * 3;
      const float* wp = &sW[(((ph >> 1) * 9 + tap)) << 3];
      float dy = wp[0]*a0 + wp[1]*a1 + wp[2]*a2 + wp[3]*a3;
      float dx = wp[4]*a0 + wp[5]*a1 + wp[6]*a2 + wp[7]*a3;
      float py  = dy + (float)(h + kr - 1);
      float pxp = dx + (float)(pxl + kc - 1);
      float y0f = floorf(py), x0f = floorf(pxp);
      float ly = py - y0f, lx = pxp - x0f;
      int y0 = (int)y0f, x0 = (int)x0f;
      float m_y0 = (y0 >=  0 && y0 <= 63) ? 1.f : 0.f;
      float m_y1 = (y0 >= -1 && y0 <= 62) ? 1.f : 0.f;
      float m_x0 = (x0 >=  0 && x0 <= 63) ? 1.f : 0.f;
      float m_x1 = (x0 >= -1 && x0 <= 62) ? 1.f : 0.f;
      float w00 = (1.f - ly) * (1.f - lx) * m_y0 * m_x0;
      float w01 = (1.f - ly) * lx         * m_y0 * m_x1;
      float w10 = ly         * (1.f - lx) * m_y1 * m_x0;
      float w11 = ly         * lx         * m_y1 * m_x1;
      int yc0 = min(max(y0, 0), 63),     yc1 = min(max(y0 + 1, 0), 63);
      int xc0 = min(max(x0, 0), 63),     xc1 = min(max(x0 + 1, 0), 63);
      int ry0 = min(max(yc0 - (h0 - 3), 0), 7);
      int ry1 = min(max(yc1 - (h0 - 3), 0), 7);
      const unsigned short* Xc = sX[ph & 1];
      const int z0 = (xc0 >> 1) & 3, z1 = (xc1 >> 1) & 3;
      const int e00 = ((ry0 << 6) + xc0) << 5, e01 = ((ry0 << 6) + xc1) << 5;
      const int e10 = ((ry1 << 6) + xc0) << 5, e11 = ((ry1 << 6) + xc1) << 5;
      uint4 Av[4], Bv[4], Cv[4], Dv[4];
#pragma unroll
      for (int j = 0; j < 4; ++j) {
        Av[j] = *(const uint4*)&Xc[e00 + ((j ^ z0) << 3)];
        Bv[j] = *(const uint4*)&Xc[e01 + ((j ^ z1) << 3)];
        Cv[j] = *(const uint4*)&Xc[e10 + ((j ^ z0) << 3)];
        Dv[j] = *(const uint4*)&Xc[e11 + ((j ^ z1) << 3)];
      }
#pragma unroll
      for (int j = 0; j < 4; ++j) {
        unsigned ua[4] = {Av[j].x, Av[j].y, Av[j].z, Av[j].w};
        unsigned ub[4] = {Bv[j].x, Bv[j].y, Bv[j].z, Bv[j].w};
        unsigned uc[4] = {Cv[j].x, Cv[j].y, Cv[j].z, Cv[j].w};
        unsigned ud[4] = {Dv[j].x, Dv[j].y, Dv[j].z, Dv[j].w};
        unsigned ov[4];
#pragma unroll
        for (int q = 0; q < 4; ++q) {
          f32x2 v = unpk(ua[q]) * w00 + unpk(ub[q]) * w01
                  + unpk(uc[q]) * w10 + unpk(ud[q]) * w11;
          ov[q] = pkbf(v.x, v.y);
        }
        *(u32x4*)&sB[buf][(pxn << 6) + ((((tapslot << 2) + j) ^ (pxn & 7)) << 3)] =
            (u32x4){ov[0], ov[1], ov[2], ov[3]};
      }
    };

    asm volatile("s_waitcnt lgkmcnt(0)" ::: "memory");  // sX[0]+sW writes done
    asm volatile("s_barrier" ::: "memory");             // B1

    produce(tapslot, 0);                                // tile 0 (taps 0,1)
    asm volatile("s_waitcnt lgkmcnt(0)" ::: "memory");
    asm volatile("s_barrier" ::: "memory");             // B2

    for (int it = 0; it < 36; ++it) {
      // ---- static staging schedule: slab s rows r0..r0+nr-1 this round ----
      // s=1: rounds 0-2 (3,3,2 rows).  s>=2: 4-round groups with a gap round
      // every 9 (buffer-liveness derived: slab s free/deadline windows).
      int s = -1, r0 = 0, nr = 0;
      if (it <= 2) { s = 1; r0 = it * 3; nr = (it == 2) ? 2 : 3; }
      else if (it >= 4 && it <= 29) {
        const int u = it - 4;
        const int pair = (u * 57) >> 9;      // u/9
        const int v = u - pair * 9;
        if (v < 4)      { s = 2 + (pair << 1); r0 = v << 1; nr = 2; }
        else if (v < 8) { s = 3 + (pair << 1); r0 = (v - 4) << 1; nr = 2; }
      }
      float xr[3][8];
      if (s > 0) {                            // issue loads early (hide under produce)
        const float* xph = xb + ((size_t)((s << 5) + (sc8 << 3)) << 12) + spx;
#pragma unroll
        for (int rr = 0; rr < 3; ++rr)
          if (rr < nr) {
            const int grow = min(max(h0 - 3 + r0 + rr, 0), 63);
#pragma unroll
            for (int jj = 0; jj < 8; ++jj) xr[rr][jj] = xph[(jj << 12) + (grow << 6)];
          }
      }
      // ---- produce tile it+1 into sB[(it+1)&1] ----
      if (it < 35) produce(((it + 1) << 1) + tapslot, (it + 1) & 1);
      // ---- commit staged rows (loads have drained under produce) ----
      if (s > 0) {
#pragma unroll
        for (int rr = 0; rr < 3; ++rr)
          if (rr < nr) {
            *(u32x4*)&sX[s & 1][((((r0 + rr) << 6) + spx) << 5) + wslot] =
                (u32x4){pkbf(xr[rr][0], xr[rr][1]), pkbf(xr[rr][2], xr[rr][3]),
                        pkbf(xr[rr][4], xr[rr][5]), pkbf(xr[rr][6], xr[rr][7])};
          }
      }
      asm volatile("s_waitcnt lgkmcnt(0)" ::: "memory");  // LDS writes visible
      asm volatile("s_barrier" ::: "memory");
    }
  }
}

// Normalize + affine + ReLU from atomic sums (full-line nt store).
__global__ __launch_bounds__(256) void norm_kernel(float* __restrict__ o,
    const float* __restrict__ st, const float* __restrict__ gamma,
    const float* __restrict__ beta) {
  int idx = blockIdx.x * 256 + threadIdx.x;    // float4s: 2,097,152
  f32x4* p = (f32x4*)o;
  int c = (idx >> 10) & 255;
  int b = idx >> 18;
  int g = b * 32 + (c >> 3);
  const float invn = 1.f / 32768.f;
  float mu  = st[g] * invn;
  float var = st[256 + g] * invn - mu * mu;
  float ga = gamma[c] * rsqrtf(var + EPSV);
  float be = beta[c] - mu * ga;
  f32x4 v = p[idx];
  v.x = fmaxf(fmaf(v.x, ga, be), 0.f);
  v.y = fmaxf(fmaf(v.y, ga, be), 0.f);
  v.z = fmaxf(fmaf(v.z, ga, be), 0.f);
  v.w = fmaxf(fmaf(v.w, ga, be), 0.f);
  __builtin_nontemporal_store(v, &p[idx]);
}

extern "C" void kernel_launch(void* const* d_in, const int* in_sizes, int n_in,
                              void* d_out, int out_size, void* d_ws, size_t ws_size,
                              hipStream_t stream) {
  const float* x     = (const float*)d_in[0];
  const float* shp   = (const float*)d_in[1];
  const float* woff  = (const float*)d_in[2];
  const float* wdef  = (const float*)d_in[3];
  const float* gamma = (const float*)d_in[4];
  const float* beta  = (const float*)d_in[5];
  float* out = (float*)d_out;
  __hip_bfloat16* w2 = (__hip_bfloat16*)d_ws;
  float* st          = (float*)((char*)d_ws + W2_BYTES);

  hipLaunchKernelGGL(wt2_kernel,   dim3(2304), dim3(256), 0, stream, wdef, w2, st);
  hipLaunchKernelGGL(fused_kernel, dim3(256),  dim3(512), 0, stream, x, shp, woff, w2, out, st);
  hipLaunchKernelGGL(norm_kernel,  dim3(8192), dim3(256), 0, stream, out, st, gamma, beta);
}

// Round 6
// 178.692 us; speedup vs baseline: 1.1254x; 1.0047x over previous
//
#include <hip/hip_runtime.h>
#include <hip/hip_bf16.h>

#define EPSV 1e-5f

typedef __attribute__((ext_vector_type(8))) short short8;
typedef __attribute__((ext_vector_type(4))) float f32x4;
typedef __attribute__((ext_vector_type(2))) float f32x2;
typedef __attribute__((ext_vector_type(4))) unsigned u32x4;

// ws layout: w2 (1,179,648 B) | st (2,048 B)
#define W2_BYTES 1179648ull

// w_deform (o, C_in, 3, 3) fp32 -> w2 bf16 [o][K], K = p*288 + k*32 + c,
// C_in = p*32 + c (p = phase 0..7).  Also zero st.
__global__ __launch_bounds__(256) void wt2_kernel(const float* __restrict__ wd,
                                                  __hip_bfloat16* __restrict__ w2,
                                                  float* __restrict__ st) {
  int idx = blockIdx.x * 256 + threadIdx.x;   // o*2304 + p*288 + k*32 + c
  int c  = idx & 31;
  int r  = idx >> 5;          // o*72 + p*9 + k
  int k  = r % 9;
  int r2 = r / 9;             // o*8 + p
  int p  = r2 & 7;
  int o  = r2 >> 3;
  w2[idx] = __float2bfloat16(wd[(o * 256 + p * 32 + c) * 9 + k]);
  if (blockIdx.x < 2) st[blockIdx.x * 256 + threadIdx.x] = 0.f;
}

static __device__ __forceinline__ f32x2 unpk(unsigned u) {
  union { unsigned i; float f; } lo, hi;
  lo.i = u << 16;
  hi.i = u & 0xffff0000u;
  return (f32x2){lo.f, hi.f};
}

static __device__ __forceinline__ unsigned pkbf(float a, float b) {
  __hip_bfloat162 p = __float22bfloat162_rn(make_float2(a, b));
  return *(unsigned*)&p;
}

// Fused sample+GEMM, 12 waves: 8 consumers + 4 producers (setprio 1).
// Block = (b, 2-row band), 768 thr, grid 256 (1 block/CU; 3 waves/SIMD =
// 2 consumers + 1 producer -> producer gather/blend latency hidden by 2
// MFMA waves on the same SIMD).
// K=64 rounds (2 taps/round), 36 rounds, ONE raw s_barrier per round.
//   consumers: each wave owns a DISTINCT 32-row M-stripe x full N=128
//     (acc[2][8]=64 VGPR, afc[2][2]=16 VGPR -> ~100 VGPR, no spill at the
//     170 cap; w2 read exactly once per block -> no redundant L2 traffic).
//   producers: identical to R4 (proven): thread = (pixel, tap-slot) x 32 ch,
//     16 LDS gathers + blend; x-window staged 2-3 rows/round.
__global__ __launch_bounds__(768, 3) void fused_kernel(
    const float* __restrict__ x, const float* __restrict__ shp,
    const float* __restrict__ woff, const __hip_bfloat16* __restrict__ w2,
    float* __restrict__ out, float* __restrict__ st) {
  __shared__ __align__(16) unsigned short sX[2][8 * 64 * 32];  // 2 x 32 KB x-window
  __shared__ __align__(16) unsigned short sB[2][128 * 64];     // 2 x 16 KB K=64 tiles
  __shared__ float sW[288];

  const int b    = blockIdx.x & 7;       // XCD swizzle: batch -> XCD
  const int band = blockIdx.x >> 3;      // 0..31
  const int h0   = band << 1;
  const int t    = threadIdx.x;
  const int wv   = t >> 6, lane = t & 63;
  const int quad = lane >> 4, l15 = lane & 15;

  const float* xb = x + ((size_t)b << 20);
  const unsigned short* w2b = (const unsigned short*)w2;

  if (t < 288) sW[t] = woff[t];

  if (wv < 8) {
    // ============================ CONSUMER ============================
    const int cw = wv;                       // M-stripe: rows cw*32..+31
    const unsigned short* aro =
        w2b + (size_t)((cw << 5) + l15) * 2304 + (quad << 3);

    f32x4 acc[2][8];                         // [mo][np]
#pragma unroll
    for (int mo = 0; mo < 2; ++mo)
#pragma unroll
      for (int np = 0; np < 8; ++np) acc[mo][np] = (f32x4){0.f, 0.f, 0.f, 0.f};

    short8 afc[2][2];                        // A frags for round `it`
#pragma unroll
    for (int ks = 0; ks < 2; ++ks)
#pragma unroll
      for (int mo = 0; mo < 2; ++mo)
        afc[ks][mo] = *(const short8*)(aro + (size_t)(mo << 4) * 2304 + (ks << 5));

    asm volatile("s_waitcnt lgkmcnt(0)" ::: "memory");  // sW writes
    asm volatile("s_barrier" ::: "memory");             // B1: sX[0]+sW ready
    asm volatile("s_barrier" ::: "memory");             // B2: tile0 in sB[0]

    for (int it = 0; it < 36; ++it) {
      const unsigned short* Bc = sB[it & 1];
#pragma unroll
      for (int np = 0; np < 8; ++np) {
        const int row = (np << 4) + l15;
#pragma unroll
        for (int ks = 0; ks < 2; ++ks) {
          short8 bf = *(const short8*)&Bc[(row << 6) +
                         ((((ks << 2) + quad) ^ (row & 7)) << 3)];
#pragma unroll
          for (int mo = 0; mo < 2; ++mo)
            acc[mo][np] = __builtin_amdgcn_mfma_f32_16x16x32_bf16(afc[ks][mo], bf, acc[mo][np], 0, 0, 0);
        }
      }
      // prefetch A for it+1 AFTER last use; stays in flight across barrier.
      if (it < 35) {
#pragma unroll
        for (int ks = 0; ks < 2; ++ks)
#pragma unroll
          for (int mo = 0; mo < 2; ++mo)
            afc[ks][mo] = *(const short8*)(aro + (size_t)(mo << 4) * 2304 +
                                           (size_t)((it + 1) << 6) + (ks << 5));
      }
      asm volatile("s_barrier" ::: "memory");
    }

    // GN partial stats (group = 8 consecutive o; quad-pairs share a gid)
#pragma unroll
    for (int mo = 0; mo < 2; ++mo) {
      float s = 0.f, q = 0.f;
#pragma unroll
      for (int np = 0; np < 8; ++np)
#pragma unroll
        for (int r = 0; r < 4; ++r) { float v = acc[mo][np][r]; s += v; q += v * v; }
#pragma unroll
      for (int m = 1; m < 16; m <<= 1) { s += __shfl_xor(s, m, 64); q += __shfl_xor(q, m, 64); }
      if (l15 == 0) {
        int gid = (b << 5) + (cw << 2) + (mo << 1) + (quad >> 1);
        atomicAdd(&st[gid], s);
        atomicAdd(&st[256 + gid], q);
      }
    }

    // C store: col(n)=l15, row(o)=quad*4+r per 16x16 block
    float* ob = out + (((size_t)((b << 8) + (cw << 5))) << 12) + (band << 7);
#pragma unroll
    for (int mo = 0; mo < 2; ++mo)
#pragma unroll
      for (int np = 0; np < 8; ++np)
#pragma unroll
        for (int r = 0; r < 4; ++r)
          ob[((size_t)((mo << 4) + (quad << 2) + r) << 12) + (np << 4) + l15] = acc[mo][np][r];
  } else {
    // ============================ PRODUCER ============================
    __builtin_amdgcn_s_setprio(1);           // producer = critical role (T5:
                                             // 2C+1P per SIMD = role diversity)
    const int pid     = t - 512;             // 0..255
    const int pxn     = pid & 127;           // band-local pixel n = hh*64+pxl
    const int tapslot = pid >> 7;            // 0/1: which tap of the K=64 pair
    const int pxl     = pxn & 63;
    const int h       = h0 + (pxn >> 6);
    const int spx     = pid & 63;            // x-stage: pixel
    const int sc8     = (pid >> 6) & 3;      // x-stage: 8-ch slot
    const int wslot   = (sc8 ^ ((spx >> 1) & 3)) << 3;

    float a0 = shp[((size_t)(b * 4 + 0) << 12) + (h << 6) + pxl];
    float a1 = shp[((size_t)(b * 4 + 1) << 12) + (h << 6) + pxl];
    float a2 = shp[((size_t)(b * 4 + 2) << 12) + (h << 6) + pxl];
    float a3 = shp[((size_t)(b * 4 + 3) << 12) + (h << 6) + pxl];

    // ---- prologue: stage sX[0] (slab 0 window, rows h0-3..h0+4 clamped) ----
    {
      const float* xph = xb + ((size_t)(sc8 << 3) << 12) + spx;
#pragma unroll
      for (int j = 0; j < 8; ++j) {
        const int grow = min(max(h0 - 3 + j, 0), 63);
        float v[8];
#pragma unroll
        for (int jj = 0; jj < 8; ++jj) v[jj] = xph[(jj << 12) + (grow << 6)];
        *(u32x4*)&sX[0][((((j << 6) + spx) << 5)) + wslot] =
            (u32x4){pkbf(v[0], v[1]), pkbf(v[2], v[3]), pkbf(v[4], v[5]), pkbf(v[6], v[7])};
      }
    }

    // sample global tap g (32 channels) for pixel (h,pxl) -> sB[buf]
    auto produce = [&](int g, int buf) {
      const int ph  = (g * 57) >> 9;         // g/9  (g < 72)
      const int tap = g - ph * 9;
      const int kr  = (tap * 11) >> 5;       // tap/3
      const int kc  = tap - kr * 3;
      const float* wp = &sW[(((ph >> 1) * 9 + tap)) << 3];
      float dy = wp[0]*a0 + wp[1]*a1 + wp[2]*a2 + wp[3]*a3;
      float dx = wp[4]*a0 + wp[5]*a1 + wp[6]*a2 + wp[7]*a3;
      float py  = dy + (float)(h + kr - 1);
      float pxp = dx + (float)(pxl + kc - 1);
      float y0f = floorf(py), x0f = floorf(pxp);
      float ly = py - y0f, lx = pxp - x0f;
      int y0 = (int)y0f, x0 = (int)x0f;
      float m_y0 = (y0 >=  0 && y0 <= 63) ? 1.f : 0.f;
      float m_y1 = (y0 >= -1 && y0 <= 62) ? 1.f : 0.f;
      float m_x0 = (x0 >=  0 && x0 <= 63) ? 1.f : 0.f;
      float m_x1 = (x0 >= -1 && x0 <= 62) ? 1.f : 0.f;
      float w00 = (1.f - ly) * (1.f - lx) * m_y0 * m_x0;
      float w01 = (1.f - ly) * lx         * m_y0 * m_x1;
      float w10 = ly         * (1.f - lx) * m_y1 * m_x0;
      float w11 = ly         * lx         * m_y1 * m_x1;
      int yc0 = min(max(y0, 0), 63),     yc1 = min(max(y0 + 1, 0), 63);
      int xc0 = min(max(x0, 0), 63),     xc1 = min(max(x0 + 1, 0), 63);
      int ry0 = min(max(yc0 - (h0 - 3), 0), 7);
      int ry1 = min(max(yc1 - (h0 - 3), 0), 7);
      const unsigned short* Xc = sX[ph & 1];
      const int z0 = (xc0 >> 1) & 3, z1 = (xc1 >> 1) & 3;
      const int e00 = ((ry0 << 6) + xc0) << 5, e01 = ((ry0 << 6) + xc1) << 5;
      const int e10 = ((ry1 << 6) + xc0) << 5, e11 = ((ry1 << 6) + xc1) << 5;
      uint4 Av[4], Bv[4], Cv[4], Dv[4];
#pragma unroll
      for (int j = 0; j < 4; ++j) {
        Av[j] = *(const uint4*)&Xc[e00 + ((j ^ z0) << 3)];
        Bv[j] = *(const uint4*)&Xc[e01 + ((j ^ z1) << 3)];
        Cv[j] = *(const uint4*)&Xc[e10 + ((j ^ z0) << 3)];
        Dv[j] = *(const uint4*)&Xc[e11 + ((j ^ z1) << 3)];
      }
#pragma unroll
      for (int j = 0; j < 4; ++j) {
        unsigned ua[4] = {Av[j].x, Av[j].y, Av[j].z, Av[j].w};
        unsigned ub[4] = {Bv[j].x, Bv[j].y, Bv[j].z, Bv[j].w};
        unsigned uc[4] = {Cv[j].x, Cv[j].y, Cv[j].z, Cv[j].w};
        unsigned ud[4] = {Dv[j].x, Dv[j].y, Dv[j].z, Dv[j].w};
        unsigned ov[4];
#pragma unroll
        for (int q = 0; q < 4; ++q) {
          f32x2 v = unpk(ua[q]) * w00 + unpk(ub[q]) * w01
                  + unpk(uc[q]) * w10 + unpk(ud[q]) * w11;
          ov[q] = pkbf(v.x, v.y);
        }
        *(u32x4*)&sB[buf][(pxn << 6) + ((((tapslot << 2) + j) ^ (pxn & 7)) << 3)] =
            (u32x4){ov[0], ov[1], ov[2], ov[3]};
      }
    };

    asm volatile("s_waitcnt lgkmcnt(0)" ::: "memory");  // sX[0]+sW writes done
    asm volatile("s_barrier" ::: "memory");             // B1

    produce(tapslot, 0);                                // tile 0 (taps 0,1)
    asm volatile("s_waitcnt lgkmcnt(0)" ::: "memory");
    asm volatile("s_barrier" ::: "memory");             // B2

    for (int it = 0; it < 36; ++it) {
      // ---- static staging schedule: slab s rows r0..r0+nr-1 this round ----
      // s=1: rounds 0-2 (3,3,2 rows).  s>=2: 4-round groups with a gap round
      // every 9 (buffer-liveness derived: slab s free/deadline windows).
      int s = -1, r0 = 0, nr = 0;
      if (it <= 2) { s = 1; r0 = it * 3; nr = (it == 2) ? 2 : 3; }
      else if (it >= 4 && it <= 29) {
        const int u = it - 4;
        const int pair = (u * 57) >> 9;      // u/9
        const int v = u - pair * 9;
        if (v < 4)      { s = 2 + (pair << 1); r0 = v << 1; nr = 2; }
        else if (v < 8) { s = 3 + (pair << 1); r0 = (v - 4) << 1; nr = 2; }
      }
      float xr[3][8];
      if (s > 0) {                            // issue loads early (hide under produce)
        const float* xph = xb + ((size_t)((s << 5) + (sc8 << 3)) << 12) + spx;
#pragma unroll
        for (int rr = 0; rr < 3; ++rr)
          if (rr < nr) {
            const int grow = min(max(h0 - 3 + r0 + rr, 0), 63);
#pragma unroll
            for (int jj = 0; jj < 8; ++jj) xr[rr][jj] = xph[(jj << 12) + (grow << 6)];
          }
      }
      // ---- produce tile it+1 into sB[(it+1)&1] ----
      if (it < 35) produce(((it + 1) << 1) + tapslot, (it + 1) & 1);
      // ---- commit staged rows (loads have drained under produce) ----
      if (s > 0) {
#pragma unroll
        for (int rr = 0; rr < 3; ++rr)
          if (rr < nr) {
            *(u32x4*)&sX[s & 1][((((r0 + rr) << 6) + spx) << 5) + wslot] =
                (u32x4){pkbf(xr[rr][0], xr[rr][1]), pkbf(xr[rr][2], xr[rr][3]),
                        pkbf(xr[rr][4], xr[rr][5]), pkbf(xr[rr][6], xr[rr][7])};
          }
      }
      asm volatile("s_waitcnt lgkmcnt(0)" ::: "memory");  // LDS writes visible
      asm volatile("s_barrier" ::: "memory");
    }
  }
}

// Normalize + affine + ReLU from atomic sums (full-line nt store).
__global__ __launch_bounds__(256) void norm_kernel(float* __restrict__ o,
    const float* __restrict__ st, const float* __restrict__ gamma,
    const float* __restrict__ beta) {
  int idx = blockIdx.x * 256 + threadIdx.x;    // float4s: 2,097,152
  f32x4* p = (f32x4*)o;
  int c = (idx >> 10) & 255;
  int b = idx >> 18;
  int g = b * 32 + (c >> 3);
  const float invn = 1.f / 32768.f;
  float mu  = st[g] * invn;
  float var = st[256 + g] * invn - mu * mu;
  float ga = gamma[c] * rsqrtf(var + EPSV);
  float be = beta[c] - mu * ga;
  f32x4 v = p[idx];
  v.x = fmaxf(fmaf(v.x, ga, be), 0.f);
  v.y = fmaxf(fmaf(v.y, ga, be), 0.f);
  v.z = fmaxf(fmaf(v.z, ga, be), 0.f);
  v.w = fmaxf(fmaf(v.w, ga, be), 0.f);
  __builtin_nontemporal_store(v, &p[idx]);
}

extern "C" void kernel_launch(void* const* d_in, const int* in_sizes, int n_in,
                              void* d_out, int out_size, void* d_ws, size_t ws_size,
                              hipStream_t stream) {
  const float* x     = (const float*)d_in[0];
  const float* shp   = (const float*)d_in[1];
  const float* woff  = (const float*)d_in[2];
  const float* wdef  = (const float*)d_in[3];
  const float* gamma = (const float*)d_in[4];
  const float* beta  = (const float*)d_in[5];
  float* out = (float*)d_out;
  __hip_bfloat16* w2 = (__hip_bfloat16*)d_ws;
  float* st          = (float*)((char*)d_ws + W2_BYTES);

  hipLaunchKernelGGL(wt2_kernel,   dim3(2304), dim3(256), 0, stream, wdef, w2, st);
  hipLaunchKernelGGL(fused_kernel, dim3(256),  dim3(768), 0, stream, x, shp, woff, w2, out, st);
  hipLaunchKernelGGL(norm_kernel,  dim3(8192), dim3(256), 0, stream, out, st, gamma, beta);
}